// Round 4
// baseline (12457.726 us; speedup 1.0000x reference)
//
#include <hip/hip_runtime.h>

#define D_ 512
#define H_ 8
#define HD_ 64
#define B_ 2
#define S_ 12
#define N_ 512
#define BS_ 24            // B*S
#define M_ 192            // H*B*S
#define T_ 12288          // B*S*N
#define PROJ_ELEMS (M_ * N_ * HD_)   // 6291456 floats = 25.165824 MB

__device__ __forceinline__ unsigned short f2bf(float x) {
    unsigned u = __float_as_uint(x);
    unsigned r = (u + 0x7FFFu + ((u >> 16) & 1u)) >> 16;
    return (unsigned short)r;
}

// P (bf16, 192*512*512 = 100.66 MB) is split across 4 buffers of 48 m each:
// q, k, v inputs (dead after proj; harness restores them before every launch)
// plus ws slot 7. 48 * 512*512*2 B = 25165824 B = exactly one buffer.
struct PPtrs { unsigned short* p0; unsigned short* p1; unsigned short* p2; unsigned short* p3; };

__device__ __forceinline__ unsigned short* p_of_m(const PPtrs& pp, int m) {
    const int sel = m / 48;
    unsigned short* base = sel == 0 ? pp.p0 : sel == 1 ? pp.p1 : sel == 2 ? pp.p2 : pp.p3;
    return base + (size_t)(m - sel * 48) * (512 * 512);
}

struct ProjArgs {
    const float* src[7];
    const float* w[7];
    const float* b[7];
    float* dst[7];
};

// out[token, dcol] = sum_k A[token,k]*W[k,dcol] + b[dcol], stored split-head:
// h = dcol>>6, hd = dcol&63, m = h*24 + (token>>9), n = token&511
__global__ __launch_bounds__(256) void proj_kernel(ProjArgs args) {
    const int z = blockIdx.z;
    const float* __restrict__ A = args.src[z];
    const float* __restrict__ W = args.w[z];
    const float* __restrict__ bias = args.b[z];
    float* __restrict__ O = args.dst[z];

    __shared__ float AsT[32][68];
    __shared__ float Bs[32][68];

    const int tid = threadIdx.x;
    const int tx = tid & 15;
    const int ty = tid >> 4;
    const int row0 = blockIdx.x * 64;
    const int col0 = blockIdx.y * 64;

    float acc[4][4] = {};

    for (int k0 = 0; k0 < 512; k0 += 32) {
        {
            const int r = tid >> 2;
            const int c0 = (tid & 3) * 8;
            const float* src = &A[(size_t)(row0 + r) * 512 + k0 + c0];
            float4 v0 = *(const float4*)(src);
            float4 v1 = *(const float4*)(src + 4);
            AsT[c0 + 0][r] = v0.x; AsT[c0 + 1][r] = v0.y;
            AsT[c0 + 2][r] = v0.z; AsT[c0 + 3][r] = v0.w;
            AsT[c0 + 4][r] = v1.x; AsT[c0 + 5][r] = v1.y;
            AsT[c0 + 6][r] = v1.z; AsT[c0 + 7][r] = v1.w;

            const int rb = tid >> 3;
            const int cb = (tid & 7) * 8;
            const float* srcB = &W[(size_t)(k0 + rb) * 512 + col0 + cb];
            float4 w0 = *(const float4*)(srcB);
            float4 w1 = *(const float4*)(srcB + 4);
            *(float4*)&Bs[rb][cb] = w0;
            *(float4*)&Bs[rb][cb + 4] = w1;
        }
        __syncthreads();
        #pragma unroll
        for (int kk = 0; kk < 32; ++kk) {
            float4 a4 = *(const float4*)&AsT[kk][ty * 4];
            float4 b4 = *(const float4*)&Bs[kk][tx * 4];
            float av[4] = {a4.x, a4.y, a4.z, a4.w};
            float bv[4] = {b4.x, b4.y, b4.z, b4.w};
            #pragma unroll
            for (int r = 0; r < 4; ++r)
                #pragma unroll
                for (int c = 0; c < 4; ++c)
                    acc[r][c] += av[r] * bv[c];
        }
        __syncthreads();
    }

    #pragma unroll
    for (int r = 0; r < 4; ++r) {
        const int trow = row0 + ty * 4 + r;
        const int bs = trow >> 9;
        const int n = trow & 511;
        #pragma unroll
        for (int c = 0; c < 4; ++c) {
            const int dcol = col0 + tx * 4 + c;
            const int h = dcol >> 6;
            const int hd = dcol & 63;
            const int m = h * BS_ + bs;
            O[((size_t)(m * 512 + n) << 6) + hd] = acc[r][c] + bias[dcol];
        }
    }
}

// ---------------- fused attention (scores -> lambda -> logits -> softmax) --------------
// block: 32 rows of one m; 512 threads = 8 waves x 4 rows; thread j-tile: lane*8..lane*8+7
// Kbuf: [512 j][16 blk of 4 floats], physical blk = logical blk ^ ((j>>3)&7)
// LDS total = exactly 128 KiB. Q fragments read from global (wave-broadcast, L1/L2-hit).
// Staging: reg-staged (global_load_dwordx4 -> ds_write_b128), per-lane swizzled SOURCE,
// linear LDS dest. (R3 used global_load_lds here and failed numerically — bisect.)

__device__ __forceinline__ void stage_K(const float* __restrict__ g, float* Kb, int tid) {
    #pragma unroll
    for (int c0 = 0; c0 < 16; c0 += 4) {
        float4 t[4];
        #pragma unroll
        for (int u = 0; u < 4; ++u) {
            const int idx = (c0 + u) * 512 + tid;   // 16-byte chunk index
            const int j = idx >> 4;
            const int b = (idx & 15) ^ ((j >> 3) & 7);   // logical block stored at this slot
            t[u] = *(const float4*)(g + ((size_t)j << 6) + (b << 2));
        }
        #pragma unroll
        for (int u = 0; u < 4; ++u) {
            const int idx = (c0 + u) * 512 + tid;
            *(float4*)(Kb + (size_t)idx * 4) = t[u];
        }
    }
}

__device__ __forceinline__ void score_pass(const float* __restrict__ qg, const float* Kb,
                                           int wave, int lane, int xr, float acc[4][8]) {
    #pragma unroll
    for (int d0 = 0; d0 < 64; d0 += 4) {
        const int kcol = ((d0 >> 2) ^ xr) << 2;
        float4 qf[4];
        #pragma unroll
        for (int r = 0; r < 4; ++r)
            qf[r] = *(const float4*)&qg[(wave * 4 + r) * 64 + d0];
        #pragma unroll
        for (int jj = 0; jj < 8; ++jj) {
            const float4 kf = *(const float4*)&Kb[(lane * 8 + jj) * 64 + kcol];
            #pragma unroll
            for (int r = 0; r < 4; ++r) {
                acc[r][jj] = fmaf(qf[r].x, kf.x, acc[r][jj]);
                acc[r][jj] = fmaf(qf[r].y, kf.y, acc[r][jj]);
                acc[r][jj] = fmaf(qf[r].z, kf.z, acc[r][jj]);
                acc[r][jj] = fmaf(qf[r].w, kf.w, acc[r][jj]);
            }
        }
    }
}

__global__ __launch_bounds__(512, 2) void attn2_kernel(
    const float* __restrict__ gq, const float* __restrict__ gk,
    const float* __restrict__ lq, const float* __restrict__ lk,
    const float* __restrict__ mq, const float* __restrict__ mk,
    PPtrs pp)
{
    __shared__ float Kbuf[512 * 64];    // 128 KiB exactly, swizzled

    const int bid = blockIdx.x;
    const int gid = (bid & 7) * 384 + (bid >> 3);   // XCD-chunked (3072 % 8 == 0)
    const int m = gid >> 4;
    const int i0 = (gid & 15) * 32;

    const int tid = threadIdx.x;
    const int wave = tid >> 6;
    const int lane = tid & 63;
    const int xr = lane & 7;
    const size_t base = (size_t)m * (512 * 64);
    const size_t qrow = base + (size_t)i0 * 64;     // q fragments for this block's rows

    // ---- pass 1: masking scores (mq . mk^T) ----
    stage_K(mk + base, Kbuf, tid);
    __syncthreads();
    float att[4][8] = {};
    score_pass(mq + qrow, Kbuf, wave, lane, xr, att);
    __syncthreads();   // everyone done reading Kbuf before restage

    // ---- stats: argmax (first occurrence), sum|j-k| closed form, mean_v ----
    int kidx[4]; float sdv[4], mnv[4];
    #pragma unroll
    for (int r = 0; r < 4; ++r) {
        float mx = att[r][0];
        int mi = lane * 8;
        #pragma unroll
        for (int jj = 1; jj < 8; ++jj) {
            if (att[r][jj] > mx) { mx = att[r][jj]; mi = lane * 8 + jj; }
        }
        #pragma unroll
        for (int off = 32; off >= 1; off >>= 1) {
            const float v2 = __shfl_xor(mx, off, 64);
            const int i2 = __shfl_xor(mi, off, 64);
            if (v2 > mx || (v2 == mx && i2 < mi)) { mx = v2; mi = i2; }
        }
        const int kk2 = mi;
        const float sd = (float)(kk2 * (kk2 + 1) / 2 + (511 - kk2) * (512 - kk2) / 2);
        float part = 0.f;
        #pragma unroll
        for (int jj = 0; jj < 8; ++jj) {
            const int j = lane * 8 + jj;
            const float dis = fabsf((float)(j - kk2)) / sd;
            part += fmaxf(att[r][jj], 0.f) * dis;
        }
        #pragma unroll
        for (int off = 32; off >= 1; off >>= 1) part += __shfl_xor(part, off, 64);
        kidx[r] = kk2; sdv[r] = sd; mnv[r] = part * (1.f / 512.f);
    }

    // lambda bits; frees att registers for reuse as gw accumulator
    unsigned lamb = 0;
    #pragma unroll
    for (int r = 0; r < 4; ++r)
        #pragma unroll
        for (int jj = 0; jj < 8; ++jj) {
            const int j = lane * 8 + jj;
            const float dis = fabsf((float)(j - kidx[r])) / sdv[r];
            if (dis * att[r][jj] - mnv[r] >= 0.f) lamb |= 1u << (r * 8 + jj);
        }

    // ---- pass 2: gw into att regs ----
    stage_K(gk + base, Kbuf, tid);
    __syncthreads();
    #pragma unroll
    for (int r = 0; r < 4; ++r)
        #pragma unroll
        for (int jj = 0; jj < 8; ++jj) att[r][jj] = 0.f;
    score_pass(gq + qrow, Kbuf, wave, lane, xr, att);
    __syncthreads();

    // ---- pass 3: lw, combine into causal logits ----
    stage_K(lk + base, Kbuf, tid);
    __syncthreads();
    float lwv[4][8] = {};
    score_pass(lq + qrow, Kbuf, wave, lane, xr, lwv);

    #pragma unroll
    for (int r = 0; r < 4; ++r) {
        const int i = i0 + wave * 4 + r;
        #pragma unroll
        for (int jj = 0; jj < 8; ++jj) {
            const int j = lane * 8 + jj;
            const float lam = ((lamb >> (r * 8 + jj)) & 1u) ? 1.f : 0.f;
            att[r][jj] = (j <= i)
                ? (0.1f * (att[r][jj] * 0.125f) + (lwv[r][jj] * 0.125f) * lam)
                : -__builtin_inff();
        }
    }

    // ---- softmax + bf16 store ----
    unsigned short* psg = p_of_m(pp, m);
    #pragma unroll
    for (int r = 0; r < 4; ++r) {
        const int i = i0 + wave * 4 + r;
        float mxl = att[r][0];
        #pragma unroll
        for (int jj = 1; jj < 8; ++jj) mxl = fmaxf(mxl, att[r][jj]);
        #pragma unroll
        for (int off = 32; off >= 1; off >>= 1) mxl = fmaxf(mxl, __shfl_xor(mxl, off, 64));
        float e[8], sum = 0.f;
        #pragma unroll
        for (int jj = 0; jj < 8; ++jj) { e[jj] = __expf(att[r][jj] - mxl); sum += e[jj]; }
        #pragma unroll
        for (int off = 32; off >= 1; off >>= 1) sum += __shfl_xor(sum, off, 64);
        const float inv = 1.f / sum;
        union { unsigned short u[8]; int4 v; } pk;
        #pragma unroll
        for (int jj = 0; jj < 8; ++jj) pk.u[jj] = f2bf(e[jj] * inv);
        *(int4*)(psg + (size_t)i * 512 + lane * 8) = pk.v;
    }
}

// ---------------- PV: aout[m][i][d] = sum_j P_bf16[m][i][j] * gv[m][j][d] --------------
// block: one m, 128 rows; 256 thr, thread 8r x 4d; k-tiles of 32
__global__ __launch_bounds__(256) void pv_kernel(PPtrs pp,
                                                 const float* __restrict__ gv,
                                                 float* __restrict__ aout)
{
    __shared__ float AsT[32][132];   // [k][row]
    __shared__ float Bs[32][68];     // [k][d]

    const int bid = blockIdx.x;
    const int gid = (bid & 7) * 96 + (bid >> 3);    // 768 % 8 == 0
    const int m = gid >> 2;
    const int i0 = (gid & 3) * 128;
    const int tid = threadIdx.x;
    const int tx = tid & 15;
    const int ty = tid >> 4;
    const unsigned short* __restrict__ ps = p_of_m(pp, m);
    const size_t vbase = (size_t)m * 512 * 64;

    float acc[8][4] = {};

    for (int k0 = 0; k0 < 512; k0 += 32) {
        #pragma unroll
        for (int s = 0; s < 2; ++s) {
            const int chunk = s * 256 + tid;     // 0..511
            const int row = chunk >> 2;          // 0..127
            const int kc = (chunk & 3) * 8;
            const unsigned short* src = ps + (size_t)(i0 + row) * 512 + k0 + kc;
            int4 w = *(const int4*)src;
            const unsigned* wu = (const unsigned*)&w;
            #pragma unroll
            for (int q = 0; q < 4; ++q) {
                AsT[kc + 2 * q][row]     = __uint_as_float((wu[q] & 0xFFFFu) << 16);
                AsT[kc + 2 * q + 1][row] = __uint_as_float((wu[q] >> 16) << 16);
            }
        }
        #pragma unroll
        for (int s = 0; s < 2; ++s) {
            const int f = (s * 256 + tid) * 4;   // 2048 floats
            const int kk = f >> 6, d = f & 63;
            *(float4*)&Bs[kk][d] = *(const float4*)&gv[vbase + (size_t)k0 * 64 + f];
        }
        __syncthreads();
        #pragma unroll
        for (int kk = 0; kk < 32; ++kk) {
            float4 b4 = *(const float4*)&Bs[kk][tx * 4];
            float4 a0 = *(const float4*)&AsT[kk][ty * 8];
            float4 a1 = *(const float4*)&AsT[kk][ty * 8 + 4];
            float av[8] = {a0.x, a0.y, a0.z, a0.w, a1.x, a1.y, a1.z, a1.w};
            float bv[4] = {b4.x, b4.y, b4.z, b4.w};
            #pragma unroll
            for (int r = 0; r < 8; ++r)
                #pragma unroll
                for (int c = 0; c < 4; ++c)
                    acc[r][c] += av[r] * bv[c];
        }
        __syncthreads();
    }

    #pragma unroll
    for (int r = 0; r < 8; ++r)
        #pragma unroll
        for (int c = 0; c < 4; ++c)
            aout[vbase + (size_t)(i0 + ty * 8 + r) * 64 + tx * 4 + c] = acc[r][c];
}

// out[token, dcol] = sum_k X_perm[token, k]*W[k,dcol] + b[dcol]
__global__ __launch_bounds__(256) void oproj_kernel(const float* __restrict__ X,
                                                    const float* __restrict__ W,
                                                    const float* __restrict__ bias,
                                                    float* __restrict__ Out) {
    __shared__ float AsT[32][68];
    __shared__ float Bs[32][68];

    const int tid = threadIdx.x;
    const int tx = tid & 15;
    const int ty = tid >> 4;
    const int row0 = blockIdx.x * 64;
    const int col0 = blockIdx.y * 64;

    float acc[4][4] = {};

    for (int k0 = 0; k0 < 512; k0 += 32) {
        const int h = k0 >> 6;
        const int hd0 = k0 & 63;
        {
            const int r = tid >> 2;
            const int c0 = (tid & 3) * 8;
            const int trow = row0 + r;
            const int bs = trow >> 9;
            const int n = trow & 511;
            const float* src = &X[(size_t)((h * BS_ + bs) * 512 + n) * 64 + hd0 + c0];
            float4 v0 = *(const float4*)(src);
            float4 v1 = *(const float4*)(src + 4);
            AsT[c0 + 0][r] = v0.x; AsT[c0 + 1][r] = v0.y;
            AsT[c0 + 2][r] = v0.z; AsT[c0 + 3][r] = v0.w;
            AsT[c0 + 4][r] = v1.x; AsT[c0 + 5][r] = v1.y;
            AsT[c0 + 6][r] = v1.z; AsT[c0 + 7][r] = v1.w;

            const int rb = tid >> 3;
            const int cb = (tid & 7) * 8;
            const float* srcB = &W[(size_t)(k0 + rb) * 512 + col0 + cb];
            float4 w0 = *(const float4*)(srcB);
            float4 w1 = *(const float4*)(srcB + 4);
            *(float4*)&Bs[rb][cb] = w0;
            *(float4*)&Bs[rb][cb + 4] = w1;
        }
        __syncthreads();
        #pragma unroll
        for (int kk = 0; kk < 32; ++kk) {
            float4 a4 = *(const float4*)&AsT[kk][ty * 4];
            float4 b4 = *(const float4*)&Bs[kk][tx * 4];
            float av[4] = {a4.x, a4.y, a4.z, a4.w};
            float bv[4] = {b4.x, b4.y, b4.z, b4.w};
            #pragma unroll
            for (int r = 0; r < 4; ++r)
                #pragma unroll
                for (int c = 0; c < 4; ++c)
                    acc[r][c] += av[r] * bv[c];
        }
        __syncthreads();
    }

    #pragma unroll
    for (int r = 0; r < 4; ++r) {
        const int trow = row0 + ty * 4 + r;
        #pragma unroll
        for (int c = 0; c < 4; ++c) {
            const int dcol = col0 + tx * 4 + c;
            Out[(size_t)trow * 512 + dcol] = acc[r][c] + bias[dcol];
        }
    }
}

extern "C" void kernel_launch(void* const* d_in, const int* in_sizes, int n_in,
                              void* d_out, int out_size, void* d_ws, size_t ws_size,
                              hipStream_t stream)
{
    const float* q  = (const float*)d_in[0];
    const float* k  = (const float*)d_in[1];
    const float* v  = (const float*)d_in[2];
    const float* w_gq = (const float*)d_in[3];  const float* b_gq = (const float*)d_in[4];
    const float* w_gk = (const float*)d_in[5];  const float* b_gk = (const float*)d_in[6];
    const float* w_gv = (const float*)d_in[7];  const float* b_gv = (const float*)d_in[8];
    const float* w_cq = (const float*)d_in[9];  const float* b_cq = (const float*)d_in[10];
    const float* w_ck = (const float*)d_in[11]; const float* b_ck = (const float*)d_in[12];
    // d_in[13], d_in[14] = w_cv, b_cv : dead code in the reference
    const float* w_mq = (const float*)d_in[15]; const float* b_mq = (const float*)d_in[16];
    const float* w_mk = (const float*)d_in[17]; const float* b_mk = (const float*)d_in[18];
    const float* w_o  = (const float*)d_in[19]; const float* b_o  = (const float*)d_in[20];

    float* ws = (float*)d_ws;
    float* p_gq = ws + (size_t)0 * PROJ_ELEMS;
    float* p_gk = ws + (size_t)1 * PROJ_ELEMS;
    float* p_gv = ws + (size_t)2 * PROJ_ELEMS;
    float* p_lq = ws + (size_t)3 * PROJ_ELEMS;
    float* p_lk = ws + (size_t)4 * PROJ_ELEMS;
    float* p_mq = ws + (size_t)5 * PROJ_ELEMS;
    float* p_mk = ws + (size_t)6 * PROJ_ELEMS;
    // P (bf16) lives in the dead q/k/v input buffers + ws slot 7.
    // Total ws footprint: 8 slots = 201.3 MB (same as the passing R1 run).
    PPtrs pp;
    pp.p0 = (unsigned short*)d_in[0];
    pp.p1 = (unsigned short*)d_in[1];
    pp.p2 = (unsigned short*)d_in[2];
    pp.p3 = (unsigned short*)(ws + (size_t)7 * PROJ_ELEMS);
    float* p_ao = p_lq;   // pv output aliases lq (attn2 done with lq before pv runs)

    ProjArgs pa;
    pa.src[0] = q; pa.w[0] = w_gq; pa.b[0] = b_gq; pa.dst[0] = p_gq;
    pa.src[1] = k; pa.w[1] = w_gk; pa.b[1] = b_gk; pa.dst[1] = p_gk;
    pa.src[2] = v; pa.w[2] = w_gv; pa.b[2] = b_gv; pa.dst[2] = p_gv;
    pa.src[3] = q; pa.w[3] = w_cq; pa.b[3] = b_cq; pa.dst[3] = p_lq;
    pa.src[4] = k; pa.w[4] = w_ck; pa.b[4] = b_ck; pa.dst[4] = p_lk;
    pa.src[5] = q; pa.w[5] = w_mq; pa.b[5] = b_mq; pa.dst[5] = p_mq;
    pa.src[6] = k; pa.w[6] = w_mk; pa.b[6] = b_mk; pa.dst[6] = p_mk;

    proj_kernel<<<dim3(192, 8, 7), 256, 0, stream>>>(pa);
    attn2_kernel<<<dim3(3072), 512, 0, stream>>>(p_gq, p_gk, p_lq, p_lk, p_mq, p_mk, pp);
    pv_kernel<<<dim3(768), 256, 0, stream>>>(pp, p_gv, p_ao);
    oproj_kernel<<<dim3(192, 8), 256, 0, stream>>>(p_ao, w_o, b_o, (float*)d_out);
}